// Round 4
// baseline (3111.710 us; speedup 1.0000x reference)
//
#include <hip/hip_runtime.h>

// ---------------- constants ----------------
#define NTOK 4096         // B*P patches
#define CH   2048         // patches per stage-2 chunk
#define NCHUNK 2

typedef _Float16 f16;
typedef __attribute__((ext_vector_type(8))) _Float16 half8;
typedef __attribute__((ext_vector_type(4))) _Float16 half4;
typedef __attribute__((ext_vector_type(4))) float f32x4;

// converted-weight layout (f16 elements) inside workspace
#define OFF_INPW 0
#define OFF_WQKV (512*128)
#define OFF_WO   (OFF_WQKV + 3*512*512)
#define OFF_W1   (OFF_WO + 512*512)
#define OFF_W2   (OFF_W1 + 512*512)
#define OFF_GW   (OFF_W2 + 512*512)       // 2 layers x [gwq|gwk|gwv|gwo]
#define WBF_TOT  (OFF_GW + 8*512*512)

static __device__ __forceinline__ f32x4 mfma16(half8 a, half8 b, f32x4 c){
  return __builtin_amdgcn_mfma_f32_16x16x32_f16(a, b, c, 0, 0, 0);
}

static __device__ __forceinline__ void gld_lds16(const f16* g, f16* l){
  __builtin_amdgcn_global_load_lds(
      (const __attribute__((address_space(1))) void*)g,
      (__attribute__((address_space(3))) void*)l, 16, 0, 0);
}

// ---------------- weight conversion ----------------
__global__ __launch_bounds__(256) void conv_weights(
    const float* __restrict__ inpw, const float* __restrict__ wq, const float* __restrict__ wk,
    const float* __restrict__ wv, const float* __restrict__ wo, const float* __restrict__ w1,
    const float* __restrict__ w2, const float* __restrict__ gwq, const float* __restrict__ gwk,
    const float* __restrict__ gwv, const float* __restrict__ gwo, f16* __restrict__ wbf,
    const float* __restrict__ bq, const float* __restrict__ bk, const float* __restrict__ bv,
    const float* __restrict__ gbq, const float* __restrict__ gbk, const float* __restrict__ gbv,
    float* __restrict__ biasb)
{
  int e = blockIdx.x*256 + threadIdx.x;
  int y = blockIdx.y;
  if (y == 0){
    if (e < 512*128){
      int row = e>>7, col = e&127;
      float v = (col < 80) ? inpw[row*80 + col] : 0.f;
      wbf[OFF_INPW + e] = (f16)v;
    }
    return;
  }
  if (y == 15){
    if (e < 1536){
      biasb[e] = (e < 512) ? bq[e] : (e < 1024 ? bk[e-512] : bv[e-1024]);
    } else if (e < 3*1536){
      int idx = e - 1536, li = idx/1536, c = idx - li*1536;
      float v = (c < 512) ? gbq[li*512 + c] : (c < 1024 ? gbk[li*512 + c-512] : gbv[li*512 + c-1024]);
      biasb[e] = v;
    }
    return;
  }
  if (e >= 512*512) return;
  const float* src; int off;
  if (y <= 6){
    const float* tab[6] = {wq, wk, wv, wo, w1, w2};
    src = tab[y-1]; off = OFF_WQKV + (y-1)*512*512;
  } else {
    int idx = y-7; int li = idx>>2, part = idx&3;
    const float* tab[4] = {gwq, gwk, gwv, gwo};
    src = tab[part] + (size_t)li*512*512; off = OFF_GW + idx*512*512;
  }
  wbf[off + e] = (f16)src[e];
}

// ---------------- per-patch mask aux ----------------
__global__ __launch_bounds__(256) void build_mask(
    const int* __restrict__ mask, float* __restrict__ mb, float* __restrict__ pex)
{
  int wv = threadIdx.x>>6, lane = threadIdx.x&63;
  int n = blockIdx.x*4 + wv;
  int valid = mask[(size_t)n*64 + lane] > 0;
  unsigned long long ball = __ballot(valid);
  int hasany = (ball != 0ull);
  int masked = (lane == 0) ? (!valid && hasany) : (!valid);
  mb[(size_t)n*64 + lane] = masked ? -1e9f : 0.f;
  if (lane == 0) pex[n] = hasany ? 1.f : 0.f;
}

// ---------------- pts: [x | te1 | sin(te2) | 0-pad] -> f16 [rows][128] ----------------
__global__ __launch_bounds__(256) void pts_build(
    const float* __restrict__ x, const float* __restrict__ tt,
    const float* __restrict__ tsw, const float* __restrict__ tsb,
    const float* __restrict__ tpw, const float* __restrict__ tpb,
    f16* __restrict__ pts, int rowbase)
{
  int e = blockIdx.x*256 + threadIdx.x;        // CH*64*128 exact
  int r = e>>7, col = e&127;
  size_t grow = (size_t)rowbase + r;
  float v;
  if (col < 16) v = x[grow*16 + col];
  else if (col >= 80) v = 0.f;
  else {
    float t = tt[grow];
    if (col == 16) v = t*tsw[0] + tsb[0];
    else           v = __sinf(t*tpw[col-17] + tpb[col-17]);
  }
  pts[e] = (f16)v;
}

// ---------------- MFMA GEMM: C[M,*] = A[M,K](lda) @ W[N,K]^T, 128x128 tile ----------
// (used for K=128 h0 gemm and small-M stage-3 gemms)
template<int RESID, bool RELU, bool OUTF32, bool ZEMPTY>
__global__ __launch_bounds__(256) void gemm128(
    const f16* __restrict__ A, const f16* __restrict__ W, const float* __restrict__ bias,
    void* __restrict__ Cout, const void* __restrict__ Rsd, const float* __restrict__ pex,
    int K, int lda, int ldc, int nbase)
{
  __shared__ __align__(16) f16 As[128][64];
  __shared__ __align__(16) f16 Bs[128][64];
  const int tid = threadIdx.x;
  const int m0 = blockIdx.x*128, n0 = blockIdx.y*128;
  const int wv = tid>>6, lane = tid&63, l15 = lane&15, quad = lane>>4;
  const int wm = (wv&1)*64, wn = (wv>>1)*64;
  const int srow = lane>>3;                 // row within 8-row group
  const int schunk = (lane&7) ^ srow;       // swizzled source chunk
  f32x4 acc[4][4] = {};
  for (int kc = 0; kc < K; kc += 64){
    __syncthreads();
    #pragma unroll
    for (int i=0; i<4; i++){
      const int rA = wv*32 + i*8;
      gld_lds16(A + (size_t)(m0 + rA + srow)*lda + kc + schunk*8, &As[rA][0]);
      gld_lds16(W + (size_t)(n0 + rA + srow)*K   + kc + schunk*8, &Bs[rA][0]);
    }
    __syncthreads();
    #pragma unroll
    for (int kk=0; kk<2; kk++){
      half8 av[4], bv8[4];
      #pragma unroll
      for (int t=0; t<4; t++){
        const int ra = wm + t*16 + l15;
        av[t]  = *(const half8*)(&As[ra][(((kk*4 + quad) ^ (ra&7)))*8]);
        const int rb = wn + t*16 + l15;
        bv8[t] = *(const half8*)(&Bs[rb][(((kk*4 + quad) ^ (rb&7)))*8]);
      }
      #pragma unroll
      for (int mt=0; mt<4; mt++)
        #pragma unroll
        for (int nt=0; nt<4; nt++)
          acc[mt][nt] = mfma16(av[mt], bv8[nt], acc[mt][nt]);
    }
  }
  #pragma unroll
  for (int mt=0; mt<4; mt++){
    #pragma unroll
    for (int nt=0; nt<4; nt++){
      #pragma unroll
      for (int i=0; i<4; i++){
        int gr = m0 + wm + mt*16 + quad*4 + i;
        int gc = n0 + wn + nt*16 + l15;
        float v = acc[mt][nt][i] + bias[gc];
        if (RELU) v = fmaxf(v, 0.f);
        if (RESID == 1) v += (float)((const f16*)Rsd)[(size_t)gr*ldc + gc];
        if (ZEMPTY){ if ((gr&63)==0 && pex[nbase + (gr>>6)]==0.f) v = 0.f; }
        if (RESID == 2) v = v*pex[gr] + ((const float*)Rsd)[(size_t)gr*ldc + gc];
        if (OUTF32) ((float*)Cout)[(size_t)gr*ldc + gc] = v;
        else        ((f16*)Cout)[(size_t)gr*ldc + gc] = (f16)v;
      }
    }
  }
}

// ---------------- fused per-patch tail: QKV -> attn -> WO -> LN1 -> FFN -> LN2 -> pool
// One block = one patch (64 tokens x 512). 512 threads = 8 waves (2 waves/SIMD).
// Head-group g = wv>>1 owns heads {2g, 2g+1}; within the group, wave sub=wv&1
// splits each sub-task (Q vs K; q-rows; tokens; d-rows) so per-wave acc <= [4][4].
__global__ __launch_bounds__(512,2) void patch_block(
    const f16* __restrict__ h0g, const f16* __restrict__ wbf, const float* __restrict__ biasb,
    const float* __restrict__ bo, const float* __restrict__ b1f, const float* __restrict__ b2f,
    const float* __restrict__ g1, const float* __restrict__ be1,
    const float* __restrict__ g2, const float* __restrict__ be2,
    const float* __restrict__ eb, const float* __restrict__ mb,
    const int* __restrict__ mask, float* __restrict__ out, int nbase)
{
  __shared__ __align__(16) f16 Z[64*520];        // z plane, then h_ln plane
  __shared__ __align__(16) f16 SC[4*2*64*72];    // per-group Q/Ps + K/Vt; later FFN f plane
  __shared__ float stS[64][8], stQ[64][8];
  __shared__ float mbs[64], vArr[64];

  const int tid = threadIdx.x, wv = tid>>6, lane = tid&63, l15 = lane&15, quad = lane>>4;
  const int g = wv>>1, sub = wv&1;
  const int n = blockIdx.x, ng = nbase + n;
  const size_t rbase = (size_t)n*64;

  if (tid < 64){
    mbs[tid]  = mb[(size_t)ng*64 + tid];
    vArr[tid] = (mask[(size_t)ng*64 + tid] > 0) ? 1.f : 0.f;
  }
  __syncthreads();

  f16* Qb = SC + g*(2*64*72);    // [64][72]: Q, then Ps
  f16* Kb = Qb + 64*72;          // [64][72]: K, then V^T
  const f16* Wq = wbf + OFF_WQKV;

  // ================= Phase A: attention, 2 rounds x 4 head-groups ============
  #pragma unroll 1
  for (int hr=0; hr<2; hr++){
    const int h = g*2 + hr;
    // ---- this wave computes (sub ? K : Q) = h0 @ W^T  (64x64, K=512) ----
    {
      const f16*  Wrow = Wq + ((size_t)(sub*512 + h*64))*512;
      const float* brow = biasb + sub*512 + h*64;
      f16* Dst = sub ? Kb : Qb;
      f32x4 acc4[4][4] = {};
      #pragma unroll 4
      for (int ks=0; ks<16; ks++){
        half8 a[4], b[4];
        #pragma unroll
        for (int mt=0; mt<4; mt++)
          a[mt] = *(const half8*)(h0g + (rbase + mt*16 + l15)*512 + ks*32 + quad*8);
        #pragma unroll
        for (int nt=0; nt<4; nt++)
          b[nt] = *(const half8*)(Wrow + (size_t)(nt*16 + l15)*512 + ks*32 + quad*8);
        #pragma unroll
        for (int mt=0; mt<4; mt++)
          #pragma unroll
          for (int nt=0; nt<4; nt++)
            acc4[mt][nt] = mfma16(a[mt], b[nt], acc4[mt][nt]);
      }
      #pragma unroll
      for (int nt=0; nt<4; nt++){
        float vb = brow[nt*16 + l15];
        #pragma unroll
        for (int mt=0; mt<4; mt++)
          #pragma unroll
          for (int i=0; i<4; i++){
            int r = mt*16 + quad*4 + i, c = nt*16 + l15;
            Dst[r*72 + c] = (f16)(acc4[mt][nt][i] + vb);
          }
      }
    }
    __syncthreads();
    // ---- scores + softmax on rows [sub*32, sub*32+32); Ps overwrites Qb ----
    {
      f32x4 sacc[2][4] = {};
      #pragma unroll
      for (int kc=0; kc<2; kc++){
        half8 af[2], bf[4];
        #pragma unroll
        for (int t=0; t<2; t++)
          af[t] = *(const half8*)(Qb + (sub*32 + t*16 + l15)*72 + kc*32 + quad*8);
        #pragma unroll
        for (int t=0; t<4; t++)
          bf[t] = *(const half8*)(Kb + (t*16 + l15)*72 + kc*32 + quad*8);
        #pragma unroll
        for (int ti=0; ti<2; ti++)
          #pragma unroll
          for (int tj=0; tj<4; tj++)
            sacc[ti][tj] = mfma16(af[ti], bf[tj], sacc[ti][tj]);
      }
      #pragma unroll
      for (int ti=0; ti<2; ti++){
        #pragma unroll
        for (int i=0; i<4; i++){
          float mx = -1e30f;
          #pragma unroll
          for (int tj=0; tj<4; tj++){
            float sv = sacc[ti][tj][i]*0.125f + mbs[tj*16 + l15];
            sacc[ti][tj][i] = sv;
            mx = fmaxf(mx, sv);
          }
          #pragma unroll
          for (int off=1; off<16; off<<=1) mx = fmaxf(mx, __shfl_xor(mx, off, 64));
          float sum = 0.f;
          #pragma unroll
          for (int tj=0; tj<4; tj++){
            float pv = __expf(sacc[ti][tj][i] - mx);
            sacc[ti][tj][i] = pv; sum += pv;
          }
          #pragma unroll
          for (int off=1; off<16; off<<=1) sum += __shfl_xor(sum, off, 64);
          float inv = 1.f/sum;
          int q = sub*32 + ti*16 + quad*4 + i;
          #pragma unroll
          for (int tj=0; tj<4; tj++)
            Qb[q*72 + tj*16 + l15] = (f16)(sacc[ti][tj][i]*inv);
        }
      }
    }
    __syncthreads();
    // ---- V for tokens [sub*32, +32), all 64 d; transposed into Kb as V^T ----
    {
      f32x4 va[2][4] = {};
      #pragma unroll 4
      for (int ks=0; ks<16; ks++){
        half8 a[2], b[4];
        #pragma unroll
        for (int mt=0; mt<2; mt++)
          a[mt] = *(const half8*)(h0g + (rbase + sub*32 + mt*16 + l15)*512 + ks*32 + quad*8);
        #pragma unroll
        for (int nt=0; nt<4; nt++)
          b[nt] = *(const half8*)(Wq + (size_t)(1024 + h*64 + nt*16 + l15)*512 + ks*32 + quad*8);
        #pragma unroll
        for (int mt=0; mt<2; mt++)
          #pragma unroll
          for (int nt=0; nt<4; nt++)
            va[mt][nt] = mfma16(a[mt], b[nt], va[mt][nt]);
      }
      #pragma unroll
      for (int nt=0; nt<4; nt++){
        float vb = biasb[1024 + h*64 + nt*16 + l15];
        #pragma unroll
        for (int mt=0; mt<2; mt++)
          #pragma unroll
          for (int i=0; i<4; i++){
            int tok = sub*32 + mt*16 + quad*4 + i, d = nt*16 + l15;
            Kb[d*72 + tok] = (f16)(va[mt][nt][i] + vb);
          }
      }
    }
    __syncthreads();
    // ---- PV for d-rows [sub*32, +32): out[d][q] -> Z[q][h*64+d] ----
    {
      f32x4 zacc[2][4] = {};
      #pragma unroll
      for (int kc=0; kc<2; kc++){
        half8 vvf[2], ppf[4];
        #pragma unroll
        for (int t=0; t<2; t++)
          vvf[t] = *(const half8*)(Kb + (sub*32 + t*16 + l15)*72 + kc*32 + quad*8);
        #pragma unroll
        for (int t=0; t<4; t++)
          ppf[t] = *(const half8*)(Qb + (t*16 + l15)*72 + kc*32 + quad*8);
        #pragma unroll
        for (int ti=0; ti<2; ti++)
          #pragma unroll
          for (int tj=0; tj<4; tj++)
            zacc[ti][tj] = mfma16(vvf[ti], ppf[tj], zacc[ti][tj]);
      }
      #pragma unroll
      for (int ti=0; ti<2; ti++)
        #pragma unroll
        for (int tj=0; tj<4; tj++){
          int q = tj*16 + l15, d0 = sub*32 + ti*16 + quad*4;
          half4 pk;
          #pragma unroll
          for (int i=0; i<4; i++) pk[i] = (f16)zacc[ti][tj][i];
          *(half4*)(Z + q*520 + h*64 + d0) = pk;
        }
    }
    __syncthreads();
  }

  // per-wave 64x64 GEMM slice vs LDS A-plane [64][520] and global W [512][512]
  auto gemmNK = [&](const f16* Ap, const f16* Wg, f32x4 (&acc)[4][4]){
    #pragma unroll 4
    for (int ks=0; ks<16; ks++){
      half8 a[4], b[4];
      #pragma unroll
      for (int mt=0; mt<4; mt++)
        a[mt] = *(const half8*)(Ap + (mt*16 + l15)*520 + ks*32 + quad*8);
      #pragma unroll
      for (int nt=0; nt<4; nt++)
        b[nt] = *(const half8*)(Wg + (size_t)(wv*64 + nt*16 + l15)*512 + ks*32 + quad*8);
      #pragma unroll
      for (int mt=0; mt<4; mt++)
        #pragma unroll
        for (int nt=0; nt<4; nt++)
          acc[mt][nt] = mfma16(a[mt], b[nt], acc[mt][nt]);
    }
  };

  // ================= Phase B: WO + bo + h0 resid -> LN1 -> h_ln into Z ========
  {
    f32x4 oa[4][4] = {};
    gemmNK(Z, wbf + OFF_WO, oa);
    #pragma unroll
    for (int nt=0; nt<4; nt++){
      int c = wv*64 + nt*16 + l15;
      float bv = bo[c];
      #pragma unroll
      for (int mt=0; mt<4; mt++)
        #pragma unroll
        for (int i=0; i<4; i++){
          int r = mt*16 + quad*4 + i;
          oa[mt][nt][i] += bv + (float)h0g[(rbase + r)*512 + c];
        }
    }
    // LN1 stats (each wave covers all 64 rows x its 64 cols)
    #pragma unroll
    for (int mt=0; mt<4; mt++)
      #pragma unroll
      for (int i=0; i<4; i++){
        float s = 0.f, sq = 0.f;
        #pragma unroll
        for (int nt=0; nt<4; nt++){ float v = oa[mt][nt][i]; s += v; sq += v*v; }
        #pragma unroll
        for (int off=1; off<16; off<<=1){ s += __shfl_xor(s, off, 64); sq += __shfl_xor(sq, off, 64); }
        if (l15 == 0){
          int r = mt*16 + quad*4 + i;
          stS[r][wv] = s; stQ[r][wv] = sq;
        }
      }
    __syncthreads();
    float m_[4][4], rs_[4][4];
    #pragma unroll
    for (int mt=0; mt<4; mt++)
      #pragma unroll
      for (int i=0; i<4; i++){
        int r = mt*16 + quad*4 + i;
        float ts = 0.f, tq = 0.f;
        #pragma unroll
        for (int w8=0; w8<8; w8++){ ts += stS[r][w8]; tq += stQ[r][w8]; }
        float m = ts*(1.f/512.f);
        m_[mt][i] = m;
        rs_[mt][i] = rsqrtf(tq*(1.f/512.f) - m*m + 1e-5f);
      }
    #pragma unroll
    for (int nt=0; nt<4; nt++){
      int c = wv*64 + nt*16 + l15;
      float g1c = g1[c], be1c = be1[c];
      #pragma unroll
      for (int mt=0; mt<4; mt++)
        #pragma unroll
        for (int i=0; i<4; i++){
          int r = mt*16 + quad*4 + i;
          float hl = (oa[mt][nt][i] - m_[mt][i])*rs_[mt][i]*g1c + be1c;
          Z[r*520 + c] = (f16)hl;
        }
    }
  }
  __syncthreads();

  // ================= Phase C: FFN1 (relu) into SC plane ======================
  {
    f32x4 fa[4][4] = {};
    gemmNK(Z, wbf + OFF_W1, fa);
    #pragma unroll
    for (int nt=0; nt<4; nt++){
      int c = wv*64 + nt*16 + l15;
      float bv = b1f[c];
      #pragma unroll
      for (int mt=0; mt<4; mt++)
        #pragma unroll
        for (int i=0; i<4; i++){
          int r = mt*16 + quad*4 + i;
          SC[r*520 + c] = (f16)fmaxf(fa[mt][nt][i] + bv, 0.f);
        }
    }
  }
  __syncthreads();

  // ================= Phase D: FFN2 + resid -> LN2 -> masked pool -> out ======
  {
    f32x4 xa[4][4] = {};
    gemmNK(SC, wbf + OFF_W2, xa);
    #pragma unroll
    for (int nt=0; nt<4; nt++){
      int c = wv*64 + nt*16 + l15;
      float bv = b2f[c];
      #pragma unroll
      for (int mt=0; mt<4; mt++)
        #pragma unroll
        for (int i=0; i<4; i++){
          int r = mt*16 + quad*4 + i;
          xa[mt][nt][i] += bv + (float)Z[r*520 + c];
        }
    }
    // LN2 stats
    #pragma unroll
    for (int mt=0; mt<4; mt++)
      #pragma unroll
      for (int i=0; i<4; i++){
        float s = 0.f, sq = 0.f;
        #pragma unroll
        for (int nt=0; nt<4; nt++){ float v = xa[mt][nt][i]; s += v; sq += v*v; }
        #pragma unroll
        for (int off=1; off<16; off<<=1){ s += __shfl_xor(s, off, 64); sq += __shfl_xor(sq, off, 64); }
        if (l15 == 0){
          int r = mt*16 + quad*4 + i;
          stS[r][wv] = s; stQ[r][wv] = sq;
        }
      }
    __syncthreads();
    float m_[4][4], rs_[4][4], wA[4][4];
    #pragma unroll
    for (int mt=0; mt<4; mt++)
      #pragma unroll
      for (int i=0; i<4; i++){
        int r = mt*16 + quad*4 + i;
        float ts = 0.f, tq = 0.f;
        #pragma unroll
        for (int w8=0; w8<8; w8++){ ts += stS[r][w8]; tq += stQ[r][w8]; }
        float m = ts*(1.f/512.f);
        m_[mt][i] = m;
        rs_[mt][i] = rsqrtf(tq*(1.f/512.f) - m*m + 1e-5f);
        wA[mt][i] = vArr[r];
      }
    float cnt = 0.f;
    #pragma unroll
    for (int l=0; l<64; l++) cnt += vArr[l];
    float denom = fmaxf(cnt, 1.f);
    float pexv = cnt > 0.f ? 1.f : 0.f;
    int pidx = ng & 127;
    #pragma unroll
    for (int nt=0; nt<4; nt++){
      int c = wv*64 + nt*16 + l15;
      float p = 0.f;
      #pragma unroll
      for (int mt=0; mt<4; mt++)
        #pragma unroll
        for (int i=0; i<4; i++)
          p += wA[mt][i]*(xa[mt][nt][i] - m_[mt][i])*rs_[mt][i];
      p += __shfl_xor(p, 16, 64);
      p += __shfl_xor(p, 32, 64);
      if (quad == 0){
        float fr = __expf(-(float)(c & ~1) * (9.210340371976184f/512.f));
        float ang = (float)pidx * fr;
        float pe = (c & 1) ? cosf(ang) : sinf(ang);
        out[(size_t)ng*512 + c] = (g2[c]*p + be2[c]*cnt)/denom + eb[c]*(1.f - pexv) + pe;
      }
    }
  }
}

__global__ __launch_bounds__(256) void cvt_f32_f16(const float* __restrict__ s, f16* __restrict__ d){
  int i = blockIdx.x*256 + threadIdx.x;
  d[i] = (f16)s[i];
}

// ---------------- graph attention on merged QKV (stride 1536), P=128 keys ----------------
__global__ __launch_bounds__(256) void attn_graph(
    f16* __restrict__ qkv, const float* __restrict__ pexists)
{
  __shared__ f16 Vt[64][136];
  __shared__ f16 Ps[4][32][136];
  __shared__ float pxs[128];
  const int tid = threadIdx.x, wv = tid>>6, lane = tid&63, l15 = lane&15, quad = lane>>4;
  const int b = blockIdx.x, h = blockIdx.y;
  if (tid < 128) pxs[tid] = pexists[b*128 + tid];
  const f16* Vb = qkv + 1024 + h*64;
  for (int i=0; i<32; i++){
    int e = tid + i*256, k = e>>6, d = e&63;
    Vt[d][k] = Vb[((size_t)b*128 + k)*1536 + d];
  }
  __syncthreads();
  const f16* Qb = qkv + h*64;
  const f16* Kb = qkv + 512 + h*64;
  const int qb = wv*32;
  f32x4 sacc[2][8] = {};
  #pragma unroll
  for (int kc=0; kc<2; kc++){
    half8 af[2], bf[8];
    #pragma unroll
    for (int ti=0; ti<2; ti++)
      af[ti] = *(const half8*)(Qb + ((size_t)b*128 + qb + ti*16 + l15)*1536 + kc*32 + quad*8);
    #pragma unroll
    for (int tj=0; tj<8; tj++)
      bf[tj] = *(const half8*)(Kb + ((size_t)b*128 + tj*16 + l15)*1536 + kc*32 + quad*8);
    #pragma unroll
    for (int ti=0; ti<2; ti++)
      #pragma unroll
      for (int tj=0; tj<8; tj++)
        sacc[ti][tj] = mfma16(af[ti], bf[tj], sacc[ti][tj]);
  }
  #pragma unroll
  for (int ti=0; ti<2; ti++){
    #pragma unroll
    for (int i=0; i<4; i++){
      int q = qb + ti*16 + quad*4 + i;
      float mx = -1e30f;
      #pragma unroll
      for (int tj=0; tj<8; tj++){
        int col = tj*16 + l15;
        int dd = q - col; if (dd < 0) dd = -dd;
        float tb = __logf(__expf(-(float)dd) + 1e-12f);
        float sv = sacc[ti][tj][i]*0.125f + tb + (pxs[col] > 0.f ? 0.f : -1e9f);
        sacc[ti][tj][i] = sv;
        mx = fmaxf(mx, sv);
      }
      #pragma unroll
      for (int off=1; off<16; off<<=1) mx = fmaxf(mx, __shfl_xor(mx, off, 64));
      float sum = 0.f;
      #pragma unroll
      for (int tj=0; tj<8; tj++){
        float pv = __expf(sacc[ti][tj][i] - mx);
        sacc[ti][tj][i] = pv; sum += pv;
      }
      #pragma unroll
      for (int off=1; off<16; off<<=1) sum += __shfl_xor(sum, off, 64);
      float inv = 1.f/sum;
      int ql = ti*16 + quad*4 + i;
      #pragma unroll
      for (int tj=0; tj<8; tj++)
        Ps[wv][ql][tj*16 + l15] = (f16)(sacc[ti][tj][i]*inv);
    }
  }
  __syncthreads();
  f32x4 zacc[4][2] = {};
  #pragma unroll
  for (int kc=0; kc<4; kc++){
    half8 va[4], pb[2];
    #pragma unroll
    for (int ti2=0; ti2<4; ti2++)
      va[ti2] = *(const half8*)(&Vt[ti2*16 + l15][kc*32 + quad*8]);
    #pragma unroll
    for (int tjq=0; tjq<2; tjq++)
      pb[tjq] = *(const half8*)(&Ps[wv][tjq*16 + l15][kc*32 + quad*8]);
    #pragma unroll
    for (int ti2=0; ti2<4; ti2++)
      #pragma unroll
      for (int tjq=0; tjq<2; tjq++)
        zacc[ti2][tjq] = mfma16(va[ti2], pb[tjq], zacc[ti2][tjq]);
  }
  __syncthreads();
  #pragma unroll
  for (int ti2=0; ti2<4; ti2++)
    #pragma unroll
    for (int tjq=0; tjq<2; tjq++){
      int ql = tjq*16 + l15, d0 = ti2*16 + quad*4;
      half4 pk;
      #pragma unroll
      for (int i=0; i<4; i++) pk[i] = (f16)zacc[ti2][tjq][i];
      *(half4*)(&Ps[wv][ql][d0]) = pk;
    }
  __syncthreads();
  {
    int q = tid>>1, hf = tid&1;
    const f16* src = &Ps[q>>5][q&31][hf*32];
    #pragma unroll
    for (int j=0; j<4; j++)
      *(uint4*)(qkv + ((size_t)b*128 + q)*1536 + h*64 + hf*32 + j*8) = *(const uint4*)(src + j*8);
  }
}

// ---------------- launcher ----------------
extern "C" void kernel_launch(void* const* d_in, const int* in_sizes, int n_in,
                              void* d_out, int out_size, void* d_ws, size_t ws_size,
                              hipStream_t stream)
{
  (void)in_sizes; (void)n_in; (void)out_size; (void)ws_size;
  const float* x    = (const float*)d_in[0];
  const float* tt   = (const float*)d_in[1];
  const int*   mask = (const int*)  d_in[2];
  const float* tsw  = (const float*)d_in[3];
  const float* tsb  = (const float*)d_in[4];
  const float* tpw  = (const float*)d_in[5];
  const float* tpb  = (const float*)d_in[6];
  const float* inpw = (const float*)d_in[7];
  const float* inpb = (const float*)d_in[8];
  const float* wq   = (const float*)d_in[9];
  const float* bq   = (const float*)d_in[10];
  const float* wk   = (const float*)d_in[11];
  const float* bk   = (const float*)d_in[12];
  const float* wv   = (const float*)d_in[13];
  const float* bv   = (const float*)d_in[14];
  const float* wo   = (const float*)d_in[15];
  const float* bo   = (const float*)d_in[16];
  const float* w1   = (const float*)d_in[17];
  const float* b1   = (const float*)d_in[18];
  const float* w2   = (const float*)d_in[19];
  const float* b2   = (const float*)d_in[20];
  const float* ln1g = (const float*)d_in[21];
  const float* ln1b = (const float*)d_in[22];
  const float* ln2g = (const float*)d_in[23];
  const float* ln2b = (const float*)d_in[24];
  const float* eb   = (const float*)d_in[25];
  const float* gwq  = (const float*)d_in[26];
  const float* gbq  = (const float*)d_in[27];
  const float* gwk  = (const float*)d_in[28];
  const float* gbk  = (const float*)d_in[29];
  const float* gwv  = (const float*)d_in[30];
  const float* gbv  = (const float*)d_in[31];
  const float* gwo  = (const float*)d_in[32];
  const float* gbo  = (const float*)d_in[33];
  float* out = (float*)d_out;

  char* wp = (char*)d_ws;
  auto alloc = [&](size_t bytes)->char*{
    char* p = wp; wp += (bytes + 255) & ~(size_t)255; return p;
  };
  f16*   wbf   = (f16*)  alloc((size_t)WBF_TOT*2);
  float* mb    = (float*)alloc((size_t)NTOK*64*4);
  float* pex   = (float*)alloc((size_t)NTOK*4);
  float* biasb = (float*)alloc((size_t)3*1536*4);
  f16*   ptsb  = (f16*)  alloc((size_t)CH*64*128*2);   // 33.5 MB
  f16*   bufA  = (f16*)  alloc((size_t)CH*64*512*2);   // h0 chunk, 134 MB
  f16*   hbf   = (f16*)  alloc((size_t)NTOK*512*2);    // stage-3 h f16
  f16*   qkvg  = (f16*)  alloc((size_t)NTOK*1536*2);   // stage-3 merged qkv

  conv_weights<<<dim3(1024,16),256,0,stream>>>(inpw,wq,wk,wv,wo,w1,w2,gwq,gwk,gwv,gwo,wbf,
                                               bq,bk,bv,gbq,gbk,gbv,biasb);
  build_mask<<<NTOK/4,256,0,stream>>>(mask, mb, pex);

  for (int ch=0; ch<NCHUNK; ch++){
    int nbase = ch*CH;
    int rowbase = nbase*64;
    pts_build<<<CH*64*128/256,256,0,stream>>>(x,tt,tsw,tsb,tpw,tpb,ptsb,rowbase);
    // h0 = pts @ inp_w^T + b (zero row0 of empty patches)
    gemm128<0,false,false,true ><<<dim3(CH*64/128,4),256,0,stream>>>(ptsb, wbf+OFF_INPW, inpb, bufA, nullptr, pex, 128, 128, 512, nbase);
    // fused tail: qkv+attn+wo+ln1+ffn+ln2+pool (512 threads / 8 waves per patch)
    patch_block<<<CH,512,0,stream>>>(bufA, wbf, biasb, bo, b1, b2,
                                     ln1g, ln1b, ln2g, ln2b, eb, mb, mask, out, nbase);
  }

  for (int li=0; li<2; li++){
    cvt_f32_f16<<<NTOK*512/256,256,0,stream>>>(out, hbf);
    gemm128<0,false,false,false><<<dim3(32,12),256,0,stream>>>(hbf, wbf+OFF_GW + (size_t)li*4*512*512, biasb + 1536*(1+li), qkvg, nullptr, nullptr, 512, 512, 1536, 0);
    attn_graph<<<dim3(32,8),256,0,stream>>>(qkvg, pex);
    // h += (z @ gwo^T + gbo) * pexists (in place on f32 d_out)
    gemm128<2,false,true ,false><<<dim3(32,4),256,0,stream>>>(qkvg, wbf+OFF_GW + (size_t)(li*4+3)*512*512, gbo+li*512, out, out, pex, 512, 1536, 512, 0);
  }
}

// Round 5
// 2501.826 us; speedup vs baseline: 1.2438x; 1.2438x over previous
//
#include <hip/hip_runtime.h>

// ---------------- constants ----------------
#define NTOK 4096         // B*P patches
#define CH   512          // patches per stage-2 chunk
#define NCHUNK 8

typedef _Float16 f16;
typedef __attribute__((ext_vector_type(8))) _Float16 half8;
typedef __attribute__((ext_vector_type(4))) _Float16 half4;
typedef __attribute__((ext_vector_type(4))) float f32x4;

// converted-weight layout (f16 elements) inside workspace
#define OFF_INPW 0
#define OFF_WQKV (512*128)
#define OFF_WO   (OFF_WQKV + 3*512*512)
#define OFF_W1   (OFF_WO + 512*512)
#define OFF_W2   (OFF_W1 + 512*512)
#define OFF_GW   (OFF_W2 + 512*512)       // 2 layers x [gwq|gwk|gwv|gwo]
#define WBF_TOT  (OFF_GW + 8*512*512)

static __device__ __forceinline__ f32x4 mfma16(half8 a, half8 b, f32x4 c){
  return __builtin_amdgcn_mfma_f32_16x16x32_f16(a, b, c, 0, 0, 0);
}

static __device__ __forceinline__ void gld_lds16(const f16* g, f16* l){
  __builtin_amdgcn_global_load_lds(
      (const __attribute__((address_space(1))) void*)g,
      (__attribute__((address_space(3))) void*)l, 16, 0, 0);
}

#define FULL_BARRIER() do { \
    asm volatile("" ::: "memory"); \
    __builtin_amdgcn_s_barrier(); \
    __builtin_amdgcn_sched_barrier(0); \
  } while(0)

// ---------------- weight conversion ----------------
__global__ __launch_bounds__(256) void conv_weights(
    const float* __restrict__ inpw, const float* __restrict__ wq, const float* __restrict__ wk,
    const float* __restrict__ wv, const float* __restrict__ wo, const float* __restrict__ w1,
    const float* __restrict__ w2, const float* __restrict__ gwq, const float* __restrict__ gwk,
    const float* __restrict__ gwv, const float* __restrict__ gwo, f16* __restrict__ wbf,
    const float* __restrict__ bq, const float* __restrict__ bk, const float* __restrict__ bv,
    const float* __restrict__ gbq, const float* __restrict__ gbk, const float* __restrict__ gbv,
    float* __restrict__ biasb)
{
  int e = blockIdx.x*256 + threadIdx.x;
  int y = blockIdx.y;
  if (y == 0){
    if (e < 512*128){
      int row = e>>7, col = e&127;
      float v = (col < 80) ? inpw[row*80 + col] : 0.f;
      wbf[OFF_INPW + e] = (f16)v;
    }
    return;
  }
  if (y == 15){
    if (e < 1536){
      biasb[e] = (e < 512) ? bq[e] : (e < 1024 ? bk[e-512] : bv[e-1024]);
    } else if (e < 3*1536){
      int idx = e - 1536, li = idx/1536, c = idx - li*1536;
      float v = (c < 512) ? gbq[li*512 + c] : (c < 1024 ? gbk[li*512 + c-512] : gbv[li*512 + c-1024]);
      biasb[e] = v;
    }
    return;
  }
  if (e >= 512*512) return;
  const float* src; int off;
  if (y <= 6){
    const float* tab[6] = {wq, wk, wv, wo, w1, w2};
    src = tab[y-1]; off = OFF_WQKV + (y-1)*512*512;
  } else {
    int idx = y-7; int li = idx>>2, part = idx&3;
    const float* tab[4] = {gwq, gwk, gwv, gwo};
    src = tab[part] + (size_t)li*512*512; off = OFF_GW + idx*512*512;
  }
  wbf[off + e] = (f16)src[e];
}

// ---------------- per-patch mask aux ----------------
__global__ __launch_bounds__(256) void build_mask(
    const int* __restrict__ mask, float* __restrict__ mb, float* __restrict__ pex)
{
  int wv = threadIdx.x>>6, lane = threadIdx.x&63;
  int n = blockIdx.x*4 + wv;
  int valid = mask[(size_t)n*64 + lane] > 0;
  unsigned long long ball = __ballot(valid);
  int hasany = (ball != 0ull);
  int masked = (lane == 0) ? (!valid && hasany) : (!valid);
  mb[(size_t)n*64 + lane] = masked ? -1e9f : 0.f;
  if (lane == 0) pex[n] = hasany ? 1.f : 0.f;
}

// ---------------- pts: [x | te1 | sin(te2) | 0-pad] -> f16 [rows][128] ----------------
__global__ __launch_bounds__(256) void pts_build(
    const float* __restrict__ x, const float* __restrict__ tt,
    const float* __restrict__ tsw, const float* __restrict__ tsb,
    const float* __restrict__ tpw, const float* __restrict__ tpb,
    f16* __restrict__ pts, int rowbase)
{
  int e = blockIdx.x*256 + threadIdx.x;        // CH*64*128 exact
  int r = e>>7, col = e&127;
  size_t grow = (size_t)rowbase + r;
  float v;
  if (col < 16) v = x[grow*16 + col];
  else if (col >= 80) v = 0.f;
  else {
    float t = tt[grow];
    if (col == 16) v = t*tsw[0] + tsb[0];
    else           v = __sinf(t*tpw[col-17] + tpb[col-17]);
  }
  pts[e] = (f16)v;
}

// ---------------- MFMA GEMM: C[M,*] = A[M,K](lda) @ W[N,K]^T, 128x128 tile ----------
// (used for K=128 h0 gemm and small-M stage-3 gemms)
template<int RESID, bool RELU, bool OUTF32, bool ZEMPTY>
__global__ __launch_bounds__(256) void gemm128(
    const f16* __restrict__ A, const f16* __restrict__ W, const float* __restrict__ bias,
    void* __restrict__ Cout, const void* __restrict__ Rsd, const float* __restrict__ pex,
    int K, int lda, int ldc, int nbase, f16* __restrict__ dual)
{
  __shared__ __align__(16) f16 As[128][64];
  __shared__ __align__(16) f16 Bs[128][64];
  const int tid = threadIdx.x;
  const int m0 = blockIdx.x*128, n0 = blockIdx.y*128;
  const int wv = tid>>6, lane = tid&63, l15 = lane&15, quad = lane>>4;
  const int wm = (wv&1)*64, wn = (wv>>1)*64;
  const int srow = lane>>3;                 // row within 8-row group
  const int schunk = (lane&7) ^ srow;       // swizzled source chunk
  f32x4 acc[4][4] = {};
  for (int kc = 0; kc < K; kc += 64){
    __syncthreads();
    #pragma unroll
    for (int i=0; i<4; i++){
      const int rA = wv*32 + i*8;
      gld_lds16(A + (size_t)(m0 + rA + srow)*lda + kc + schunk*8, &As[rA][0]);
      gld_lds16(W + (size_t)(n0 + rA + srow)*K   + kc + schunk*8, &Bs[rA][0]);
    }
    __syncthreads();
    #pragma unroll
    for (int kk=0; kk<2; kk++){
      half8 av[4], bv8[4];
      #pragma unroll
      for (int t=0; t<4; t++){
        const int ra = wm + t*16 + l15;
        av[t]  = *(const half8*)(&As[ra][(((kk*4 + quad) ^ (ra&7)))*8]);
        const int rb = wn + t*16 + l15;
        bv8[t] = *(const half8*)(&Bs[rb][(((kk*4 + quad) ^ (rb&7)))*8]);
      }
      #pragma unroll
      for (int mt=0; mt<4; mt++)
        #pragma unroll
        for (int nt=0; nt<4; nt++)
          acc[mt][nt] = mfma16(av[mt], bv8[nt], acc[mt][nt]);
    }
  }
  #pragma unroll
  for (int mt=0; mt<4; mt++){
    #pragma unroll
    for (int nt=0; nt<4; nt++){
      #pragma unroll
      for (int i=0; i<4; i++){
        int gr = m0 + wm + mt*16 + quad*4 + i;
        int gc = n0 + wn + nt*16 + l15;
        float v = acc[mt][nt][i] + bias[gc];
        if (RELU) v = fmaxf(v, 0.f);
        if (RESID == 1) v += (float)((const f16*)Rsd)[(size_t)gr*ldc + gc];
        if (ZEMPTY){ if ((gr&63)==0 && pex[nbase + (gr>>6)]==0.f) v = 0.f; }
        if (RESID == 2) v = v*pex[gr] + ((const float*)Rsd)[(size_t)gr*ldc + gc];
        if (OUTF32) ((float*)Cout)[(size_t)gr*ldc + gc] = v;
        else        ((f16*)Cout)[(size_t)gr*ldc + gc] = (f16)v;
        if (RESID == 2){ if (dual) dual[(size_t)gr*ldc + gc] = (f16)v; }
      }
    }
  }
}

// ---------------- 256x256-tile 8-phase GEMM, deep staging (proven R2) ---------------
template<int RESID, bool RELU>
__global__ __launch_bounds__(512,2) void gemm256(
    const f16* __restrict__ A, const f16* __restrict__ W, const float* __restrict__ bias,
    f16* __restrict__ Cout, const f16* __restrict__ Rsd,
    int K, int lda, int ldc)
{
  __shared__ __align__(16) f16 As[2*2*128*64];
  __shared__ __align__(16) f16 Bs[2*2*128*64];

  const int tid = threadIdx.x;
  const int wv = tid>>6, lane = tid&63, l15 = lane&15, quad = lane>>4;
  const int wm = wv>>2;
  const int wn = wv&3;

  const int gx = gridDim.x, gy = gridDim.y;
  int nwg = gx*gy;
  int orig = blockIdx.x*gy + blockIdx.y;
  int qq = nwg>>3;
  int swz = (orig&7)*qq + (orig>>3);
  const int m0 = (swz/gy)*256, n0 = (swz%gy)*256;

  const int NT = K>>6;

  auto stage_half = [&](int t, int hf){
    int tc = t < NT ? t : NT-1;
    int kc = tc<<6;
    int b  = t & 1;
    #pragma unroll
    for (int i=0;i<2;i++){
      int idx = wv*2+i;
      int row = idx*8 + (lane>>3);
      int col = kc + (((lane&7) ^ (lane>>3))<<3);
      if (hf < 2)
        gld_lds16(A + (size_t)(m0 + hf*128 + row)*lda + col,
                  As + b*16384 + hf*8192 + idx*512);
      else
        gld_lds16(W + (size_t)(n0 + (hf-2)*128 + row)*K + col,
                  Bs + b*16384 + (hf-2)*8192 + idx*512);
    }
  };
  auto ldsA = [&](int b, int mt, int kk)->half8{
    int r = mt*16 + l15;
    int g = kk*4 + quad;
    return *(const half8*)(As + b*16384 + wm*8192 + r*64 + ((g ^ (r&7))<<3));
  };
  auto ldsB = [&](int b, int nt, int kk)->half8{
    int r = (wn&1)*64 + nt*16 + l15;
    int g = kk*4 + quad;
    return *(const half8*)(Bs + b*16384 + (wn>>1)*8192 + r*64 + ((g ^ (r&7))<<3));
  };

  half8 a[8], b0[4], b1[4];
  f32x4 acc[8][4] = {};
  auto mm8 = [&](int mb, half8* bq, int nb){
    __builtin_amdgcn_s_setprio(1);
    #pragma unroll
    for (int m=0;m<4;m++)
      #pragma unroll
      for (int n=0;n<2;n++)
        #pragma unroll
        for (int k=0;k<2;k++)
          acc[mb+m][nb+n] = mfma16(a[m*2+k], bq[n*2+k], acc[mb+m][nb+n]);
    __builtin_amdgcn_s_setprio(0);
  };

  stage_half(0,0); stage_half(0,1); stage_half(0,2); stage_half(0,3);
  stage_half(1,2); stage_half(1,3);
  asm volatile("s_waitcnt vmcnt(4)" ::: "memory");
  FULL_BARRIER();

  for (int t = 0; t < NT; t += 2){
    #pragma unroll
    for (int hv = 0; hv < 2; hv++){
      const int c  = t + hv;
      const int bf = hv;
      #pragma unroll
      for (int m=0;m<4;m++){ a[m*2]=ldsA(bf,m,0); a[m*2+1]=ldsA(bf,m,1); }
      #pragma unroll
      for (int n=0;n<2;n++){ b0[n*2]=ldsB(bf,n,0); b0[n*2+1]=ldsB(bf,n,1); }
      stage_half(c+1, 0);
      FULL_BARRIER();
      mm8(0, b0, 0);
      FULL_BARRIER();
      #pragma unroll
      for (int n=0;n<2;n++){ b1[n*2]=ldsB(bf,n+2,0); b1[n*2+1]=ldsB(bf,n+2,1); }
      stage_half(c+1, 1);
      FULL_BARRIER();
      mm8(0, b1, 2);
      FULL_BARRIER();
      #pragma unroll
      for (int m=0;m<4;m++){ a[m*2]=ldsA(bf,m+4,0); a[m*2+1]=ldsA(bf,m+4,1); }
      stage_half(c+2, 2);
      FULL_BARRIER();
      mm8(4, b1, 2);
      FULL_BARRIER();
      stage_half(c+2, 3);
      asm volatile("s_waitcnt vmcnt(4)" ::: "memory");
      FULL_BARRIER();
      mm8(4, b0, 0);
      FULL_BARRIER();
    }
  }

  #pragma unroll
  for (int mt=0; mt<8; mt++){
    #pragma unroll
    for (int nt=0; nt<4; nt++){
      #pragma unroll
      for (int i=0; i<4; i++){
        int gr = m0 + wm*128 + mt*16 + quad*4 + i;
        int gc = n0 + wn*64  + nt*16 + l15;
        float v = acc[mt][nt][i] + bias[gc];
        if (RELU) v = fmaxf(v, 0.f);
        if (RESID == 1) v += (float)Rsd[(size_t)gr*ldc + gc];
        Cout[(size_t)gr*ldc + gc] = (f16)v;
      }
    }
  }
}

// ---------------- full-row GEMM 128x512, K=512, with fused LN / LN+pool epilogue ----
// 512 threads = 8 waves: wm=wv>>2 (64-row half = one patch), wn=wv&3 (128-col quarter).
// EPI=1: C = LN1(acc + bias + Rsd_f16) * g + be  -> f16 Cf16
// EPI=2: LN2(acc + bias + Rsd_f16) -> masked pool + exists-bias + pos-enc -> f32 outp
//        (+ f16 copy to hcopy for stage-3)
template<int EPI>
__global__ __launch_bounds__(512,2) void gemm_row512(
    const f16* __restrict__ A, const f16* __restrict__ W, const float* __restrict__ bias,
    f16* __restrict__ Cf16, const f16* __restrict__ Rsd,
    const float* __restrict__ g, const float* __restrict__ be,
    const float* __restrict__ eb, const int* __restrict__ mask,
    float* __restrict__ outp, f16* __restrict__ hcopy,
    int lda, int nbase)
{
  __shared__ __align__(16) f16 As[128][64];
  __shared__ __align__(16) f16 Bs[512][64];
  __shared__ float stS[128][4], stQ[128][4];
  __shared__ float vArr[128];

  const int tid = threadIdx.x;
  const int wv = tid>>6, lane = tid&63, l15 = lane&15, quad = lane>>4;
  const int wm = wv>>2, wn = wv&3;
  const int m0 = blockIdx.x*128;
  const int srow = lane>>3;
  const int schunk = (lane&7) ^ srow;

  if (EPI == 2){
    if (tid < 128){
      int ngt = nbase + blockIdx.x*2 + (tid>>6);
      vArr[tid] = (mask[(size_t)ngt*64 + (tid&63)] > 0) ? 1.f : 0.f;
    }
  }

  f32x4 acc[4][8] = {};
  for (int kc = 0; kc < 512; kc += 64){
    __syncthreads();
    #pragma unroll
    for (int i=0; i<2; i++){
      const int rA = wv*16 + i*8;
      gld_lds16(A + (size_t)(m0 + rA + srow)*lda + kc + schunk*8, &As[rA][0]);
    }
    #pragma unroll
    for (int i=0; i<8; i++){
      const int rB = wv*64 + i*8;
      gld_lds16(W + (size_t)(rB + srow)*512 + kc + schunk*8, &Bs[rB][0]);
    }
    __syncthreads();
    #pragma unroll
    for (int kk=0; kk<2; kk++){
      half8 a[4], b[8];
      #pragma unroll
      for (int mt=0; mt<4; mt++){
        const int ra = wm*64 + mt*16 + l15;
        a[mt] = *(const half8*)(&As[ra][(((kk*4 + quad) ^ (ra&7)))*8]);
      }
      #pragma unroll
      for (int nt=0; nt<8; nt++){
        const int rb = wn*128 + nt*16 + l15;
        b[nt] = *(const half8*)(&Bs[rb][(((kk*4 + quad) ^ (rb&7)))*8]);
      }
      #pragma unroll
      for (int mt=0; mt<4; mt++)
        #pragma unroll
        for (int nt=0; nt<8; nt++)
          acc[mt][nt] = mfma16(a[mt], b[nt], acc[mt][nt]);
    }
  }

  // ---- bias + residual ----
  #pragma unroll
  for (int nt=0; nt<8; nt++){
    int c = wn*128 + nt*16 + l15;
    float bv = bias[c];
    #pragma unroll
    for (int mt=0; mt<4; mt++)
      #pragma unroll
      for (int i=0; i<4; i++){
        int gr = m0 + wm*64 + mt*16 + quad*4 + i;
        acc[mt][nt][i] += bv + (float)Rsd[(size_t)gr*512 + c];
      }
  }
  // ---- LN row stats (cross-wave over wn) ----
  #pragma unroll
  for (int mt=0; mt<4; mt++)
    #pragma unroll
    for (int i=0; i<4; i++){
      float s = 0.f, sq = 0.f;
      #pragma unroll
      for (int nt=0; nt<8; nt++){ float v = acc[mt][nt][i]; s += v; sq += v*v; }
      #pragma unroll
      for (int off=1; off<16; off<<=1){ s += __shfl_xor(s, off, 64); sq += __shfl_xor(sq, off, 64); }
      if (l15 == 0){
        int r = wm*64 + mt*16 + quad*4 + i;
        stS[r][wn] = s; stQ[r][wn] = sq;
      }
    }
  __syncthreads();
  float m_[4][4], rs_[4][4];
  #pragma unroll
  for (int mt=0; mt<4; mt++)
    #pragma unroll
    for (int i=0; i<4; i++){
      int r = wm*64 + mt*16 + quad*4 + i;
      float ts = stS[r][0] + stS[r][1] + stS[r][2] + stS[r][3];
      float tq = stQ[r][0] + stQ[r][1] + stQ[r][2] + stQ[r][3];
      float m = ts*(1.f/512.f);
      m_[mt][i] = m;
      rs_[mt][i] = rsqrtf(tq*(1.f/512.f) - m*m + 1e-5f);
    }

  if (EPI == 1){
    #pragma unroll
    for (int nt=0; nt<8; nt++){
      int c = wn*128 + nt*16 + l15;
      float gc_ = g[c], bec = be[c];
      #pragma unroll
      for (int mt=0; mt<4; mt++)
        #pragma unroll
        for (int i=0; i<4; i++){
          int gr = m0 + wm*64 + mt*16 + quad*4 + i;
          Cf16[(size_t)gr*512 + c] = (f16)((acc[mt][nt][i] - m_[mt][i])*rs_[mt][i]*gc_ + bec);
        }
    }
  } else {
    // masked pool over this wave's patch (rows wm*64..wm*64+63)
    float wA[4][4];
    #pragma unroll
    for (int mt=0; mt<4; mt++)
      #pragma unroll
      for (int i=0; i<4; i++)
        wA[mt][i] = vArr[wm*64 + mt*16 + quad*4 + i];
    float cnt = 0.f;
    #pragma unroll
    for (int l=0; l<64; l++) cnt += vArr[wm*64 + l];
    float denom = fmaxf(cnt, 1.f);
    float pexv = cnt > 0.f ? 1.f : 0.f;
    int ng = nbase + blockIdx.x*2 + wm;
    int pidx = ng & 127;
    #pragma unroll
    for (int nt=0; nt<8; nt++){
      int c = wn*128 + nt*16 + l15;
      float p = 0.f;
      #pragma unroll
      for (int mt=0; mt<4; mt++)
        #pragma unroll
        for (int i=0; i<4; i++)
          p += wA[mt][i]*(acc[mt][nt][i] - m_[mt][i])*rs_[mt][i];
      p += __shfl_xor(p, 16, 64);
      p += __shfl_xor(p, 32, 64);
      if (quad == 0){
        float fr = __expf(-(float)(c & ~1) * (9.210340371976184f/512.f));
        float ang = (float)pidx * fr;
        float pe = (c & 1) ? cosf(ang) : sinf(ang);
        float o = (g[c]*p + be[c]*cnt)/denom + eb[c]*(1.f - pexv) + pe;
        outp[(size_t)ng*512 + c] = o;
        hcopy[(size_t)ng*512 + c] = (f16)o;
      }
    }
  }
}

// ---------------- intra-patch MHA on merged QKV buffer (stride 1536) ----------------
__global__ __launch_bounds__(128) void attn_patch(
    f16* __restrict__ qkv, const float* __restrict__ maskbias, int nbase)
{
  __shared__ f16 Vt[2][64][72];   // V^T [d][key]; later reused as z [q][d]
  __shared__ f16 Ps[2][64][72];   // softmax probs [q][key]
  __shared__ float mbs[64];
  const int tid = threadIdx.x, wv = tid>>6, lane = tid&63, l15 = lane&15, quad = lane>>4;
  const int n = blockIdx.x, h = blockIdx.y*2 + wv;
  if (tid < 64) mbs[tid] = maskbias[(size_t)(nbase+n)*64 + tid];
  const f16* Vb = qkv + 1024 + h*64;
  for (int i=0; i<64; i++)
    Vt[wv][lane][i] = Vb[((size_t)n*64 + i)*1536 + lane];
  __syncthreads();
  const f16* Qb  = qkv + (size_t)n*64*1536 + h*64;
  const f16* Kbb = Qb + 512;
  f32x4 sacc[4][4] = {};
  #pragma unroll
  for (int kc=0; kc<2; kc++){
    half8 af[4], bf[4];
    #pragma unroll
    for (int t4=0; t4<4; t4++){
      af[t4] = *(const half8*)(Qb  + (size_t)(t4*16 + l15)*1536 + kc*32 + quad*8);
      bf[t4] = *(const half8*)(Kbb + (size_t)(t4*16 + l15)*1536 + kc*32 + quad*8);
    }
    #pragma unroll
    for (int ti=0; ti<4; ti++)
      #pragma unroll
      for (int tj=0; tj<4; tj++)
        sacc[ti][tj] = mfma16(af[ti], bf[tj], sacc[ti][tj]);
  }
  #pragma unroll
  for (int ti=0; ti<4; ti++){
    #pragma unroll
    for (int i=0; i<4; i++){
      float mx = -1e30f;
      #pragma unroll
      for (int tj=0; tj<4; tj++){
        float sv = sacc[ti][tj][i]*0.125f + mbs[tj*16 + l15];
        sacc[ti][tj][i] = sv;
        mx = fmaxf(mx, sv);
      }
      #pragma unroll
      for (int off=1; off<16; off<<=1) mx = fmaxf(mx, __shfl_xor(mx, off, 64));
      float sum = 0.f;
      #pragma unroll
      for (int tj=0; tj<4; tj++){
        float pv = __expf(sacc[ti][tj][i] - mx);
        sacc[ti][tj][i] = pv; sum += pv;
      }
      #pragma unroll
      for (int off=1; off<16; off<<=1) sum += __shfl_xor(sum, off, 64);
      float inv = 1.f/sum;
      int q = ti*16 + quad*4 + i;
      #pragma unroll
      for (int tj=0; tj<4; tj++)
        Ps[wv][q][tj*16 + l15] = (f16)(sacc[ti][tj][i]*inv);
    }
  }
  __syncthreads();
  f32x4 zacc[4][4] = {};
  #pragma unroll
  for (int kc=0; kc<2; kc++){
    half8 va[4], pb[4];
    #pragma unroll
    for (int t4=0; t4<4; t4++){
      va[t4] = *(const half8*)(&Vt[wv][t4*16 + l15][kc*32 + quad*8]);
      pb[t4] = *(const half8*)(&Ps[wv][t4*16 + l15][kc*32 + quad*8]);
    }
    #pragma unroll
    for (int ti2=0; ti2<4; ti2++)
      #pragma unroll
      for (int tj=0; tj<4; tj++)
        zacc[ti2][tj] = mfma16(va[ti2], pb[tj], zacc[ti2][tj]);
  }
  __syncthreads();
  #pragma unroll
  for (int ti2=0; ti2<4; ti2++)
    #pragma unroll
    for (int tj=0; tj<4; tj++){
      int q = tj*16 + l15, d0 = ti2*16 + quad*4;
      half4 pk;
      #pragma unroll
      for (int i=0; i<4; i++) pk[i] = (f16)zacc[ti2][tj][i];
      *(half4*)(&Vt[wv][q][d0]) = pk;
    }
  __syncthreads();
  #pragma unroll
  for (int i=0; i<8; i++){
    int q = i*8 + (lane>>3), d0 = (lane&7)*8;
    *(uint4*)(qkv + ((size_t)n*64 + q)*1536 + h*64 + d0) = *(const uint4*)(&Vt[wv][q][d0]);
  }
}

// ---------------- graph attention on merged QKV (stride 1536), P=128 keys ----------------
__global__ __launch_bounds__(256) void attn_graph(
    f16* __restrict__ qkv, const float* __restrict__ pexists)
{
  __shared__ f16 Vt[64][136];
  __shared__ f16 Ps[4][32][136];
  __shared__ float pxs[128];
  const int tid = threadIdx.x, wv = tid>>6, lane = tid&63, l15 = lane&15, quad = lane>>4;
  const int b = blockIdx.x, h = blockIdx.y;
  if (tid < 128) pxs[tid] = pexists[b*128 + tid];
  const f16* Vb = qkv + 1024 + h*64;
  for (int i=0; i<32; i++){
    int e = tid + i*256, k = e>>6, d = e&63;
    Vt[d][k] = Vb[((size_t)b*128 + k)*1536 + d];
  }
  __syncthreads();
  const f16* Qb = qkv + h*64;
  const f16* Kb = qkv + 512 + h*64;
  const int qb = wv*32;
  f32x4 sacc[2][8] = {};
  #pragma unroll
  for (int kc=0; kc<2; kc++){
    half8 af[2], bf[8];
    #pragma unroll
    for (int ti=0; ti<2; ti++)
      af[ti] = *(const half8*)(Qb + ((size_t)b*128 + qb + ti*16 + l15)*1536 + kc*32 + quad*8);
    #pragma unroll
    for (int tj=0; tj<8; tj++)
      bf[tj] = *(const half8*)(Kb + ((size_t)b*128 + tj*16 + l15)*1536 + kc*32 + quad*8);
    #pragma unroll
    for (int ti=0; ti<2; ti++)
      #pragma unroll
      for (int tj=0; tj<8; tj++)
        sacc[ti][tj] = mfma16(af[ti], bf[tj], sacc[ti][tj]);
  }
  #pragma unroll
  for (int ti=0; ti<2; ti++){
    #pragma unroll
    for (int i=0; i<4; i++){
      int q = qb + ti*16 + quad*4 + i;
      float mx = -1e30f;
      #pragma unroll
      for (int tj=0; tj<8; tj++){
        int col = tj*16 + l15;
        int dd = q - col; if (dd < 0) dd = -dd;
        float tb = __logf(__expf(-(float)dd) + 1e-12f);
        float sv = sacc[ti][tj][i]*0.125f + tb + (pxs[col] > 0.f ? 0.f : -1e9f);
        sacc[ti][tj][i] = sv;
        mx = fmaxf(mx, sv);
      }
      #pragma unroll
      for (int off=1; off<16; off<<=1) mx = fmaxf(mx, __shfl_xor(mx, off, 64));
      float sum = 0.f;
      #pragma unroll
      for (int tj=0; tj<8; tj++){
        float pv = __expf(sacc[ti][tj][i] - mx);
        sacc[ti][tj][i] = pv; sum += pv;
      }
      #pragma unroll
      for (int off=1; off<16; off<<=1) sum += __shfl_xor(sum, off, 64);
      float inv = 1.f/sum;
      int ql = ti*16 + quad*4 + i;
      #pragma unroll
      for (int tj=0; tj<8; tj++)
        Ps[wv][ql][tj*16 + l15] = (f16)(sacc[ti][tj][i]*inv);
    }
  }
  __syncthreads();
  f32x4 zacc[4][2] = {};
  #pragma unroll
  for (int kc=0; kc<4; kc++){
    half8 va[4], pb[2];
    #pragma unroll
    for (int ti2=0; ti2<4; ti2++)
      va[ti2] = *(const half8*)(&Vt[ti2*16 + l15][kc*32 + quad*8]);
    #pragma unroll
    for (int tjq=0; tjq<2; tjq++)
      pb[tjq] = *(const half8*)(&Ps[wv][tjq*16 + l15][kc*32 + quad*8]);
    #pragma unroll
    for (int ti2=0; ti2<4; ti2++)
      #pragma unroll
      for (int tjq=0; tjq<2; tjq++)
        zacc[ti2][tjq] = mfma16(va[ti2], pb[tjq], zacc[ti2][tjq]);
  }
  __syncthreads();
  #pragma unroll
  for (int ti2=0; ti2<4; ti2++)
    #pragma unroll
    for (int tjq=0; tjq<2; tjq++){
      int ql = tjq*16 + l15, d0 = ti2*16 + quad*4;
      half4 pk;
      #pragma unroll
      for (int i=0; i<4; i++) pk[i] = (f16)zacc[ti2][tjq][i];
      *(half4*)(&Ps[wv][ql][d0]) = pk;
    }
  __syncthreads();
  {
    int q = tid>>1, hf = tid&1;
    const f16* src = &Ps[q>>5][q&31][hf*32];
    #pragma unroll
    for (int j=0; j<4; j++)
      *(uint4*)(qkv + ((size_t)b*128 + q)*1536 + h*64 + hf*32 + j*8) = *(const uint4*)(src + j*8);
  }
}

// ---------------- launcher ----------------
extern "C" void kernel_launch(void* const* d_in, const int* in_sizes, int n_in,
                              void* d_out, int out_size, void* d_ws, size_t ws_size,
                              hipStream_t stream)
{
  (void)in_sizes; (void)n_in; (void)out_size; (void)ws_size;
  const float* x    = (const float*)d_in[0];
  const float* tt   = (const float*)d_in[1];
  const int*   mask = (const int*)  d_in[2];
  const float* tsw  = (const float*)d_in[3];
  const float* tsb  = (const float*)d_in[4];
  const float* tpw  = (const float*)d_in[5];
  const float* tpb  = (const float*)d_in[6];
  const float* inpw = (const float*)d_in[7];
  const float* inpb = (const float*)d_in[8];
  const float* wq   = (const float*)d_in[9];
  const float* bq   = (const float*)d_in[10];
  const float* wk   = (const float*)d_in[11];
  const float* bk   = (const float*)d_in[12];
  const float* wv   = (const float*)d_in[13];
  const float* bv   = (const float*)d_in[14];
  const float* wo   = (const float*)d_in[15];
  const float* bo   = (const float*)d_in[16];
  const float* w1   = (const float*)d_in[17];
  const float* b1   = (const float*)d_in[18];
  const float* w2   = (const float*)d_in[19];
  const float* b2   = (const float*)d_in[20];
  const float* ln1g = (const float*)d_in[21];
  const float* ln1b = (const float*)d_in[22];
  const float* ln2g = (const float*)d_in[23];
  const float* ln2b = (const float*)d_in[24];
  const float* eb   = (const float*)d_in[25];
  const float* gwq  = (const float*)d_in[26];
  const float* gbq  = (const float*)d_in[27];
  const float* gwk  = (const float*)d_in[28];
  const float* gbk  = (const float*)d_in[29];
  const float* gwv  = (const float*)d_in[30];
  const float* gbv  = (const float*)d_in[31];
  const float* gwo  = (const float*)d_in[32];
  const float* gbo  = (const float*)d_in[33];
  float* out = (float*)d_out;

  char* wp = (char*)d_ws;
  auto alloc = [&](size_t bytes)->char*{
    char* p = wp; wp += (bytes + 255) & ~(size_t)255; return p;
  };
  f16*   wbf   = (f16*)  alloc((size_t)WBF_TOT*2);
  float* mb    = (float*)alloc((size_t)NTOK*64*4);
  float* pex   = (float*)alloc((size_t)NTOK*4);
  float* biasb = (float*)alloc((size_t)3*1536*4);
  f16*   ptsb  = (f16*)  alloc((size_t)CH*64*128*2);
  f16*   bufA  = (f16*)  alloc((size_t)CH*64*512*2);   // h0
  f16*   bufB  = (f16*)  alloc((size_t)CH*64*512*2);   // ln1 out; stage-3: qkvg
  f16*   bufC  = (f16*)  alloc((size_t)CH*64*512*2);   // ffn1 out
  f16*   qkv   = (f16*)  alloc((size_t)CH*64*1536*2);  // merged q|k|v (z overwrites q)
  f16*   hbf   = (f16*)  alloc((size_t)NTOK*512*2);    // f16 copy of h (stage-3 input)

  conv_weights<<<dim3(1024,16),256,0,stream>>>(inpw,wq,wk,wv,wo,w1,w2,gwq,gwk,gwv,gwo,wbf,
                                               bq,bk,bv,gbq,gbk,gbv,biasb);
  build_mask<<<NTOK/4,256,0,stream>>>(mask, mb, pex);

  const int MB  = CH*64/128;   // 256 m-blocks (128-tile)
  const int MB2 = CH*64/256;   // 128 m-blocks (256-tile)
  const int MBR = CH*64/128;   // 256 blocks (row512-tile: 128 rows each)
  for (int ch=0; ch<NCHUNK; ch++){
    int nbase = ch*CH;
    int rowbase = nbase*64;
    pts_build<<<CH*64*128/256,256,0,stream>>>(x,tt,tsw,tsb,tpw,tpb,ptsb,rowbase);
    // h0 = pts @ inp_w^T + b (zero row0 of empty patches)
    gemm128<0,false,false,true ><<<dim3(MB,4),256,0,stream>>>(ptsb, wbf+OFF_INPW, inpb, bufA, nullptr, pex, 128, 128, 512, nbase, nullptr);
    // fused q|k|v — 256-tile 8-phase deep-pipeline
    gemm256<0,false><<<dim3(MB2,6),512,0,stream>>>(bufA, wbf+OFF_WQKV, biasb, qkv, nullptr, 512, 512, 1536);
    attn_patch<<<dim3(CH,4),128,0,stream>>>(qkv, mb, nbase);
    // WO + bo + h0-resid + LN1 -> bufB   (A = z in q-region of qkv, lda 1536)
    gemm_row512<1><<<MBR,512,0,stream>>>(qkv, wbf+OFF_WO, bo, bufB, bufA,
                                         ln1g, ln1b, nullptr, nullptr, nullptr, nullptr, 1536, nbase);
    // FFN1 (relu) -> bufC
    gemm256<0,true ><<<dim3(MB2,2),512,0,stream>>>(bufB, wbf+OFF_W1, b1, bufC, nullptr, 512, 512, 512);
    // FFN2 + b2 + resid(bufB) + LN2 + masked pool + eb + pos-enc -> out (+ hbf f16)
    gemm_row512<2><<<MBR,512,0,stream>>>(bufC, wbf+OFF_W2, b2, nullptr, bufB,
                                         ln2g, ln2b, eb, mask, out, hbf, 512, nbase);
  }

  f16* qkvg = bufB;              // reuse stage-2 buffer in stage-3
  for (int li=0; li<2; li++){
    gemm128<0,false,false,false><<<dim3(32,12),256,0,stream>>>(hbf, wbf+OFF_GW + (size_t)li*4*512*512, biasb + 1536*(1+li), qkvg, nullptr, nullptr, 512, 512, 1536, 0, nullptr);
    attn_graph<<<dim3(32,8),256,0,stream>>>(qkvg, pex);
    // h += (z @ gwo^T + gbo) * pexists (in place on f32 d_out; li=0 also refreshes hbf)
    gemm128<2,false,true ,false><<<dim3(32,4),256,0,stream>>>(qkvg, wbf+OFF_GW + (size_t)(li*4+3)*512*512, gbo+li*512, out, out, pex, 512, 1536, 512, 0, (li==0)? hbf : nullptr);
  }
}